// Round 15
// baseline (245.818 us; speedup 1.0000x reference)
//
#include <hip/hip_runtime.h>

typedef unsigned short u16;
typedef unsigned int u32;
typedef __attribute__((ext_vector_type(8))) short s16x8;
typedef __attribute__((ext_vector_type(4))) float f32x4;

#define NN 50000
#define NE 600000
#define NG 64

__device__ __forceinline__ u16 f2bf(float f) {
    u32 u = __float_as_uint(f);
    u32 r = (u + 0x7fffu + ((u >> 16) & 1u)) >> 16;
    return (u16)r;
}
__device__ __forceinline__ float bf2f(u16 h) {
    return __uint_as_float(((u32)h) << 16);
}
__device__ __forceinline__ void gll16(const void* g, void* l) {
    __builtin_amdgcn_global_load_lds((const __attribute__((address_space(1))) u32*)g,
                                     (__attribute__((address_space(3))) u32*)l, 16, 0, 0);
}

// ---------------- CSR build ----------------
__global__ void k_hist(const int* __restrict__ dst, int* __restrict__ cnt, int ne) {
    int e = blockIdx.x * blockDim.x + threadIdx.x;
    if (e < ne) atomicAdd(&cnt[dst[e]], 1);
}

__global__ __launch_bounds__(256)
void k_scan1(const int* __restrict__ cnt, int* __restrict__ bsum, int n) {
    int i = blockIdx.x * 256 + threadIdx.x;
    int v = (i < n) ? cnt[i] : 0;
#pragma unroll
    for (int off = 32; off > 0; off >>= 1) v += __shfl_down(v, off, 64);
    __shared__ int ws[4];
    int lane = threadIdx.x & 63, w = threadIdx.x >> 6;
    if (lane == 0) ws[w] = v;
    __syncthreads();
    if (threadIdx.x == 0) bsum[blockIdx.x] = ws[0] + ws[1] + ws[2] + ws[3];
}

__global__ __launch_bounds__(256)
void k_scan2(int* __restrict__ bsum, int nb) {
    int t = threadIdx.x;
    int v = (t < nb) ? bsum[t] : 0;
    int lane = t & 63, w = t >> 6;
    int inc = v;
#pragma unroll
    for (int off = 1; off < 64; off <<= 1) {
        int x = __shfl_up(inc, off, 64);
        if (lane >= off) inc += x;
    }
    __shared__ int wtot[4];
    if (lane == 63) wtot[w] = inc;
    __syncthreads();
    int wo = 0;
    for (int j = 0; j < w; ++j) wo += wtot[j];
    if (t < nb) bsum[t] = wo + inc - v;   // exclusive
}

__global__ __launch_bounds__(256)
void k_scan3(const int* __restrict__ cnt, const int* __restrict__ boff,
             int* __restrict__ rowptr, int* __restrict__ cursor,
             float* __restrict__ dinv, int n) {
    int i = blockIdx.x * 256 + threadIdx.x;
    int v = (i < n) ? cnt[i] : 0;
    int lane = threadIdx.x & 63, w = threadIdx.x >> 6;
    int inc = v;
#pragma unroll
    for (int off = 1; off < 64; off <<= 1) {
        int x = __shfl_up(inc, off, 64);
        if (lane >= off) inc += x;
    }
    __shared__ int wtot[4];
    if (lane == 63) wtot[w] = inc;
    __syncthreads();
    int wo = boff[blockIdx.x];
    for (int j = 0; j < w; ++j) wo += wtot[j];
    if (i < n) {
        int excl = wo + inc - v;
        rowptr[i] = excl;
        cursor[i] = excl;
        dinv[i] = rsqrtf(1.0f + (float)v);
        if (i == n - 1) rowptr[n] = excl + v;
    }
}

// fill stores (src, dinv[src]) pairs -> gather needs one uint2 load per edge
__global__ void k_fill(const int* __restrict__ src, const int* __restrict__ dst,
                       const float* __restrict__ dinv,
                       int* __restrict__ cursor, uint2* __restrict__ csr2, int ne) {
    int e = blockIdx.x * blockDim.x + threadIdx.x;
    if (e < ne) {
        int pos = atomicAdd(&cursor[dst[e]], 1);
        int s = src[e];
        csr2[pos] = make_uint2((u32)s, __float_as_uint(dinv[s]));
    }
}

// ---------------- fused preamble ----------------
// Weights stored PRE-TILED single-bf16: wt[kgrp][n][8] with k = kgrp*8 + j
__device__ __forceinline__ void wsplit_tiled(const float* __restrict__ W,
                                             u16* __restrict__ hi, int gid) {
    int n = gid & 255, kgrp = gid >> 8;
    int kbase = kgrp * 8;
#pragma unroll
    for (int j = 0; j < 8; ++j) {
        float w = W[(size_t)(kbase + j) * 256 + n];
        hi[(size_t)gid * 8 + j] = f2bf(w);
    }
}

// block ranges: [0,XB) xbf(sliced) | [16) W1 | [32) W2 | [64) sums | [CB) cnt | [1] counts
__global__ __launch_bounds__(256)
void k_preamble(const float* __restrict__ x, u16* __restrict__ xbf_s,
                const float* __restrict__ W1, u16* __restrict__ w1hi,
                const float* __restrict__ W2, u16* __restrict__ w2hi,
                float* __restrict__ sums, int* __restrict__ cnt,
                const int* __restrict__ batch, float* __restrict__ counts) {
    const int XB = (NN * 32 + 255) / 256;        // x as float4: N*128/4 elems
    const int CB = (NN + 255) / 256;
    int b = blockIdx.x, t = threadIdx.x;
    if (b < XB) {
        int i = b * 256 + t;
        if (i < NN * 32) {
            float4 v = ((const float4*)x)[i];
            int node = i >> 5;
            int q = i & 31;              // float4 index within row; ch0 = q*4
            int slice = q >> 3;          // 32-ch slices (4 slices for C=128)
            int uoff = (q & 7) * 2;      // uint offset within 16-uint slice row
            uint2 o;
            o.x = (u32)f2bf(v.x) | ((u32)f2bf(v.y) << 16);
            o.y = (u32)f2bf(v.z) | ((u32)f2bf(v.w) << 16);
            ((uint2*)xbf_s)[(((size_t)slice * NN + node) * 16 + uoff) >> 1] = o;
        }
        return;
    }
    b -= XB;
    if (b < 16) { wsplit_tiled(W1, w1hi, b * 256 + t); return; }   // 4096 groups
    b -= 16;
    if (b < 32) { wsplit_tiled(W2, w2hi, b * 256 + t); return; }   // 8192 groups
    b -= 32;
    if (b < 64) { sums[b * 256 + t] = 0.f; return; }
    b -= 64;
    if (b < CB) {
        int i = b * 256 + t;
        if (i < NN) cnt[i] = 0;
        return;
    }
    b -= CB;
    if (b == 0) {   // counts via binary search on sorted batch
        __shared__ int lb[65];
        if (t <= 64) {
            int lo = 0, hi = NN;
            while (lo < hi) {
                int mid = (lo + hi) >> 1;
                if (batch[mid] < t) lo = mid + 1; else hi = mid;
            }
            lb[t] = lo;
        }
        __syncthreads();
        if (t < 64) counts[t] = (float)(lb[t + 1] - lb[t]);
    }
}

// ---------------- XCD-pinned sliced gather ----------------
// Source hbs: [NS slices][n nodes][16 uints = 32ch bf16]; slice = 3.2MB.
// slice = blockIdx & (NS-1): consecutive blocks round-robin across the 8 XCDs,
// pinning each slice to one XCD's L2 (heuristic; affects speed only).
// 16 lanes/node; all 16 lanes broadcast-load the same csr2 entry (no shuffles,
// no wave-uniform trip count); 4-deep unrolled row loads.
template<int C>
__global__ __launch_bounds__(256)
void k_agg_xcd(const int* __restrict__ rowptr, const uint2* __restrict__ csr2,
               const float* __restrict__ dinv, const u16* __restrict__ hbs,
               u16* __restrict__ out, int n) {
    constexpr int NS = C / 32;
    constexpr int LS = (NS == 8) ? 3 : 2;
    int slice = blockIdx.x & (NS - 1);
    int nb = blockIdx.x >> LS;
    int li = threadIdx.x & 15;
    int node = nb * 16 + (threadIdx.x >> 4);
    if (node >= n) node = n - 1;                 // NN%16==0: exact cover
    int beg = rowptr[node];
    int m = rowptr[node + 1] - beg;
    float di = dinv[node];
    const u32* sb = (const u32*)hbs + (size_t)slice * n * 16;

    // self term
    u32 v = sb[(size_t)node * 16 + li];
    float a0 = bf2f((u16)v) * di, b0 = bf2f((u16)(v >> 16)) * di;
    float a1 = 0.f, b1 = 0.f;

    const uint2* ep = csr2 + beg;
    int e = 0;
    for (; e + 4 <= m; e += 4) {
        uint2 e0 = ep[e], e1 = ep[e + 1], e2 = ep[e + 2], e3 = ep[e + 3];
        u32 r0 = sb[(size_t)e0.x * 16 + li];
        u32 r1 = sb[(size_t)e1.x * 16 + li];
        u32 r2 = sb[(size_t)e2.x * 16 + li];
        u32 r3 = sb[(size_t)e3.x * 16 + li];
        float w0 = __uint_as_float(e0.y), w1 = __uint_as_float(e1.y);
        float w2 = __uint_as_float(e2.y), w3 = __uint_as_float(e3.y);
        a0 += bf2f((u16)r0) * w0; b0 += bf2f((u16)(r0 >> 16)) * w0;
        a1 += bf2f((u16)r1) * w1; b1 += bf2f((u16)(r1 >> 16)) * w1;
        a0 += bf2f((u16)r2) * w2; b0 += bf2f((u16)(r2 >> 16)) * w2;
        a1 += bf2f((u16)r3) * w3; b1 += bf2f((u16)(r3 >> 16)) * w3;
    }
    for (; e < m; ++e) {
        uint2 e0 = ep[e];
        u32 r0 = sb[(size_t)e0.x * 16 + li];
        float w0 = __uint_as_float(e0.y);
        a0 += bf2f((u16)r0) * w0; b0 += bf2f((u16)(r0 >> 16)) * w0;
    }
    float fa = (a0 + a1) * di, fb = (b0 + b1) * di;
    ((u32*)out)[(size_t)node * (C / 2) + slice * 16 + li] =
        (u32)f2bf(fa) | ((u32)f2bf(fb) << 16);
}

// ---------------- MFMA GEMM (R9 structure, single-bf16 B) ----------------
// BM=128, BN=256, BK=32, 512 thr / 8 waves. A staged in 16KB dbuf LDS via
// global_load_lds; B pre-tiled [kgrp][n][8] bf16 from L2.
// !POOL epilogue writes SLICED layout [col>>5][row][col&31] (gather-2 source).
template<bool POOL>
__global__ __launch_bounds__(512, 4)
void k_gemm_mfma(const u16* __restrict__ A, const u16* __restrict__ Bh,
                 const float* __restrict__ bias, u16* __restrict__ out_bf,
                 const int* __restrict__ batch, float* __restrict__ pool,
                 int M, int K) {
    __shared__ u16 ldsA[2][4096];   // 2 x 8KB: [128 rows][4 slots of 8 bf16]
    const int tid = threadIdx.x, lane = tid & 63, wid = tid >> 6;
    const int bm = blockIdx.x * 128;
    const int wr = (wid >> 2) * 64, wc = (wid & 3) * 64;
    const int lr = lane & 15, kg = lane >> 4;

    const int srow = wid * 16 + (lane >> 2);            // local row 0..127
    const int sslot = lane & 3;
    const int ssw = (srow ^ (srow >> 2)) & 3;
    int srg = bm + srow; if (srg >= M) srg = M - 1;
    const u16* sbase = A + (size_t)srg * K + ((sslot ^ ssw) << 3);

    const u16* bh_p = Bh + (u32)kg * 2048 + (u32)(wc + lr) * 8;

    f32x4 acc[4][4];
#pragma unroll
    for (int i = 0; i < 4; ++i)
#pragma unroll
        for (int j = 0; j < 4; ++j) acc[i][j] = (f32x4){0.f, 0.f, 0.f, 0.f};

    const int nt = K >> 5;
    gll16(sbase, &ldsA[0][wid * 512]);
    __syncthreads();

    for (int t = 0; t < nt; ++t) {
        int cur = t & 1;
        if (t + 1 < nt)
            gll16(sbase + ((t + 1) << 5), &ldsA[cur ^ 1][wid * 512]);

        s16x8 bh[4];
#pragma unroll
        for (int fn = 0; fn < 4; ++fn)
            bh[fn] = *(const s16x8*)&bh_p[(u32)t * 8192 + (u32)fn * 128];
        const u16* lb = ldsA[cur];
        s16x8 a[4];
#pragma unroll
        for (int fm = 0; fm < 4; ++fm) {
            int r = wr + fm * 16 + lr;
            a[fm] = *(const s16x8*)&lb[r * 32 + ((kg ^ ((r ^ (r >> 2)) & 3)) << 3)];
        }
#pragma unroll
        for (int fn = 0; fn < 4; ++fn)
#pragma unroll
            for (int fm = 0; fm < 4; ++fm)
                acc[fm][fn] = __builtin_amdgcn_mfma_f32_16x16x32_bf16(a[fm], bh[fn], acc[fm][fn], 0, 0, 0);
        __syncthreads();
    }

    // epilogue: row = bm + wr + fm*16 + kg*4 + r ; col = wc + fn*16 + lr
#pragma unroll
    for (int fn = 0; fn < 4; ++fn) {
        int col = wc + fn * 16 + lr;
        float bv = bias[col];
        if (!POOL) {
            size_t sbase_o = ((size_t)(col >> 5) * (size_t)M) * 32 + (col & 31);
#pragma unroll
            for (int fm = 0; fm < 4; ++fm) {
                int rbase = bm + wr + fm * 16 + kg * 4;
#pragma unroll
                for (int r = 0; r < 4; ++r) {
                    int row = rbase + r;
                    if (row < M)
                        out_bf[sbase_o + (size_t)row * 32] = f2bf(fmaxf(acc[fm][fn][r] + bv, 0.f));
                }
            }
        } else {
            int gcur = -1;
            float run = 0.f;
#pragma unroll
            for (int fm = 0; fm < 4; ++fm) {
                int rbase = bm + wr + fm * 16 + kg * 4;
#pragma unroll
                for (int r = 0; r < 4; ++r) {
                    int row = rbase + r;
                    if (row < M) {
                        int g = batch[row];
                        float v = fmaxf(acc[fm][fn][r] + bv, 0.f);
                        if (g != gcur) {
                            if (gcur >= 0) atomicAdd(&pool[gcur * 256 + col], run);
                            gcur = g;
                            run = 0.f;
                        }
                        run += v;
                    }
                }
            }
            if (gcur >= 0) atomicAdd(&pool[gcur * 256 + col], run);
        }
    }
}

// ---------------- dense head ----------------
__global__ __launch_bounds__(128)
void k_dense(const float* __restrict__ sums, const float* __restrict__ counts,
             const float* __restrict__ W3, const float* __restrict__ b3,
             const float* __restrict__ W4, const float* __restrict__ b4,
             float* __restrict__ out) {
    __shared__ float g[256];
    __shared__ float hid[128];
    int gi = blockIdx.x;
    int t = threadIdx.x;
    float inv = 1.0f / fmaxf(counts[gi], 1.0f);
    for (int c = t; c < 256; c += 128) g[c] = sums[gi * 256 + c] * inv;
    __syncthreads();
    float acc = b3[t];
    for (int k = 0; k < 256; ++k) acc += g[k] * W3[k * 128 + t];
    hid[t] = fmaxf(acc, 0.0f);
    __syncthreads();
    if (t < 10) {
        float o = b4[t];
        for (int k = 0; k < 128; ++k) o += hid[k] * W4[k * 10 + t];
        out[gi * 10 + t] = o;
    }
}

extern "C" void kernel_launch(void* const* d_in, const int* in_sizes, int n_in,
                              void* d_out, int out_size, void* d_ws, size_t ws_size,
                              hipStream_t stream) {
    const float* x   = (const float*)d_in[0];
    const int*  eidx = (const int*)d_in[1];    // [2, NE]
    const int*  batch= (const int*)d_in[2];
    const float* W1 = (const float*)d_in[3];
    const float* b1 = (const float*)d_in[4];
    const float* W2 = (const float*)d_in[5];
    const float* b2 = (const float*)d_in[6];
    const float* W3 = (const float*)d_in[7];
    const float* b3 = (const float*)d_in[8];
    const float* W4 = (const float*)d_in[9];
    const float* b4 = (const float*)d_in[10];
    float* out = (float*)d_out;

    const int N = NN, E = NE, G = NG;
    const int* src = eidx;
    const int* dst = eidx + E;
    const int NB = (N + 255) / 256;

    // workspace layout (256B-aligned slices)
    char* p = (char*)d_ws;
    auto alloc = [&](size_t bytes) { char* r = p; p += (bytes + 255) & ~(size_t)255; return r; };
    u16*   h1bf_s = (u16*)alloc((size_t)N * 256 * 2);   // SLICED bf16 h1 [8][N][32]
    u16*   xbf_s  = (u16*)alloc((size_t)N * 128 * 2);   // SLICED bf16 x  [4][N][32]
    float* dinv   = (float*)alloc((size_t)N * 4);
    float* sums   = (float*)alloc((size_t)G * 256 * 4);
    float* counts = (float*)alloc((size_t)G * 4);
    int*   cnt    = (int*)alloc((size_t)N * 4);         // reused as cursor after scan
    int*   rowptr = (int*)alloc((size_t)(N + 1) * 4);
    int*   bsum   = (int*)alloc((size_t)NB * 4);
    uint2* csr2   = (uint2*)alloc((size_t)E * 8);       // (src, dinv[src])
    u16*   agg1   = (u16*)alloc((size_t)N * 128 * 2);   // row-major aggregated x
    u16*   agg2   = (u16*)alloc((size_t)N * 256 * 2);   // row-major aggregated h1
    u16*   w1hi   = (u16*)alloc((size_t)256 * 128 * 2); // pre-tiled [kgrp][n][8]
    u16*   w2hi   = (u16*)alloc((size_t)256 * 256 * 2);
    int*   cursor = cnt;

    // fused preamble: xbf(sliced), tiled wsplits, zero sums, zero cnt, counts
    const int XB = (NN * 32 + 255) / 256;
    const int CB = (NN + 255) / 256;
    int pre_blocks = XB + 16 + 32 + 64 + CB + 1;
    k_preamble<<<pre_blocks, 256, 0, stream>>>(x, xbf_s, W1, w1hi, W2, w2hi,
                                               sums, cnt, batch, counts);

    // CSR build + dinv
    k_hist<<<(E + 255) / 256, 256, 0, stream>>>(dst, cnt, E);
    k_scan1<<<NB, 256, 0, stream>>>(cnt, bsum, N);
    k_scan2<<<1, 256, 0, stream>>>(bsum, NB);
    k_scan3<<<NB, 256, 0, stream>>>(cnt, bsum, rowptr, cursor, dinv, N);
    k_fill<<<(E + 255) / 256, 256, 0, stream>>>(src, dst, dinv, cursor, csr2, E);

    const int nodeblocks = (N + 15) / 16;   // 3125

    // conv1: XCD-pinned sliced gather (4 slices) -> row-major agg1, GEMM K=128 -> h1bf SLICED
    k_agg_xcd<128><<<nodeblocks * 4, 256, 0, stream>>>(rowptr, csr2, dinv, xbf_s, agg1, N);
    int gblocks = (N + 127) / 128;
    k_gemm_mfma<false><<<gblocks, 512, 0, stream>>>(agg1, w1hi, b1, h1bf_s,
                                                    nullptr, nullptr, N, 128);

    // conv2: XCD-pinned sliced gather (8 slices) -> row-major agg2, GEMM K=256 + pool
    k_agg_xcd<256><<<nodeblocks * 8, 256, 0, stream>>>(rowptr, csr2, dinv, h1bf_s, agg2, N);
    k_gemm_mfma<true><<<gblocks, 512, 0, stream>>>(agg2, w2hi, b2, nullptr,
                                                   batch, sums, N, 256);

    // dense head
    k_dense<<<G, 128, 0, stream>>>(sums, counts, W3, b3, W4, b4, out);
}

// Round 16
// 215.286 us; speedup vs baseline: 1.1418x; 1.1418x over previous
//
#include <hip/hip_runtime.h>

typedef unsigned short u16;
typedef unsigned int u32;
typedef __attribute__((ext_vector_type(8))) short s16x8;
typedef __attribute__((ext_vector_type(4))) float f32x4;

#define NN 50000
#define NE 600000
#define NG 64

__device__ __forceinline__ u16 f2bf(float f) {
    u32 u = __float_as_uint(f);
    u32 r = (u + 0x7fffu + ((u >> 16) & 1u)) >> 16;
    return (u16)r;
}
__device__ __forceinline__ float bf2f(u16 h) {
    return __uint_as_float(((u32)h) << 16);
}
__device__ __forceinline__ void gll16(const void* g, void* l) {
    __builtin_amdgcn_global_load_lds((const __attribute__((address_space(1))) u32*)g,
                                     (__attribute__((address_space(3))) u32*)l, 16, 0, 0);
}

// ---------------- CSR build ----------------
__global__ void k_hist(const int* __restrict__ dst, int* __restrict__ cnt, int ne) {
    int e = blockIdx.x * blockDim.x + threadIdx.x;
    if (e < ne) atomicAdd(&cnt[dst[e]], 1);
}

__global__ __launch_bounds__(256)
void k_scan1(const int* __restrict__ cnt, int* __restrict__ bsum, int n) {
    int i = blockIdx.x * 256 + threadIdx.x;
    int v = (i < n) ? cnt[i] : 0;
#pragma unroll
    for (int off = 32; off > 0; off >>= 1) v += __shfl_down(v, off, 64);
    __shared__ int ws[4];
    int lane = threadIdx.x & 63, w = threadIdx.x >> 6;
    if (lane == 0) ws[w] = v;
    __syncthreads();
    if (threadIdx.x == 0) bsum[blockIdx.x] = ws[0] + ws[1] + ws[2] + ws[3];
}

__global__ __launch_bounds__(256)
void k_scan2(int* __restrict__ bsum, int nb) {
    int t = threadIdx.x;
    int v = (t < nb) ? bsum[t] : 0;
    int lane = t & 63, w = t >> 6;
    int inc = v;
#pragma unroll
    for (int off = 1; off < 64; off <<= 1) {
        int x = __shfl_up(inc, off, 64);
        if (lane >= off) inc += x;
    }
    __shared__ int wtot[4];
    if (lane == 63) wtot[w] = inc;
    __syncthreads();
    int wo = 0;
    for (int j = 0; j < w; ++j) wo += wtot[j];
    if (t < nb) bsum[t] = wo + inc - v;   // exclusive
}

__global__ __launch_bounds__(256)
void k_scan3(const int* __restrict__ cnt, const int* __restrict__ boff,
             int* __restrict__ rowptr, int* __restrict__ cursor,
             float* __restrict__ dinv, int n) {
    int i = blockIdx.x * 256 + threadIdx.x;
    int v = (i < n) ? cnt[i] : 0;
    int lane = threadIdx.x & 63, w = threadIdx.x >> 6;
    int inc = v;
#pragma unroll
    for (int off = 1; off < 64; off <<= 1) {
        int x = __shfl_up(inc, off, 64);
        if (lane >= off) inc += x;
    }
    __shared__ int wtot[4];
    if (lane == 63) wtot[w] = inc;
    __syncthreads();
    int wo = boff[blockIdx.x];
    for (int j = 0; j < w; ++j) wo += wtot[j];
    if (i < n) {
        int excl = wo + inc - v;
        rowptr[i] = excl;
        cursor[i] = excl;
        dinv[i] = rsqrtf(1.0f + (float)v);
        if (i == n - 1) rowptr[n] = excl + v;
    }
}

// fill stores (src, dinv[src]) pairs -> gather does one broadcast uint2 per edge
__global__ void k_fill(const int* __restrict__ src, const int* __restrict__ dst,
                       const float* __restrict__ dinv,
                       int* __restrict__ cursor, uint2* __restrict__ csr2, int ne) {
    int e = blockIdx.x * blockDim.x + threadIdx.x;
    if (e < ne) {
        int pos = atomicAdd(&cursor[dst[e]], 1);
        int s = src[e];
        csr2[pos] = make_uint2((u32)s, __float_as_uint(dinv[s]));
    }
}

// ---------------- fused preamble ----------------
// Weights stored PRE-TILED single-bf16: wt[kgrp][n][8] with k = kgrp*8 + j
__device__ __forceinline__ void wsplit_tiled(const float* __restrict__ W,
                                             u16* __restrict__ hi, int gid) {
    int n = gid & 255, kgrp = gid >> 8;
    int kbase = kgrp * 8;
#pragma unroll
    for (int j = 0; j < 8; ++j) {
        float w = W[(size_t)(kbase + j) * 256 + n];
        hi[(size_t)gid * 8 + j] = f2bf(w);
    }
}

// block ranges: [0,XB) xbf | [16) W1 | [32) W2 | [64) sums | [CB) cnt | [1] counts
__global__ __launch_bounds__(256)
void k_preamble(const float* __restrict__ x, u16* __restrict__ xbf,
                const float* __restrict__ W1, u16* __restrict__ w1hi,
                const float* __restrict__ W2, u16* __restrict__ w2hi,
                float* __restrict__ sums, int* __restrict__ cnt,
                const int* __restrict__ batch, float* __restrict__ counts) {
    const int XB = (NN * 32 + 255) / 256;        // x as float4: N*128/4 elems
    const int CB = (NN + 255) / 256;
    int b = blockIdx.x, t = threadIdx.x;
    if (b < XB) {
        int i = b * 256 + t;
        if (i < NN * 32) {
            float4 v = ((const float4*)x)[i];
            ushort4 o;
            o.x = f2bf(v.x); o.y = f2bf(v.y); o.z = f2bf(v.z); o.w = f2bf(v.w);
            ((ushort4*)xbf)[i] = o;
        }
        return;
    }
    b -= XB;
    if (b < 16) { wsplit_tiled(W1, w1hi, b * 256 + t); return; }   // 4096 groups
    b -= 16;
    if (b < 32) { wsplit_tiled(W2, w2hi, b * 256 + t); return; }   // 8192 groups
    b -= 32;
    if (b < 64) { sums[b * 256 + t] = 0.f; return; }
    b -= 64;
    if (b < CB) {
        int i = b * 256 + t;
        if (i < NN) cnt[i] = 0;
        return;
    }
    b -= CB;
    if (b == 0) {   // counts via binary search on sorted batch
        __shared__ int lb[65];
        if (t <= 64) {
            int lo = 0, hi = NN;
            while (lo < hi) {
                int mid = (lo + hi) >> 1;
                if (batch[mid] < t) lo = mid + 1; else hi = mid;
            }
            lb[t] = lo;
        }
        __syncthreads();
        if (t < 64) counts[t] = (float)(lb[t + 1] - lb[t]);
    }
}

// ---------------- gather aggregation: 2 nodes/wave, 32 lanes/node ----------------
// Row-major bf16 source, ONE pass. Per edge: one broadcast uint2 (src,w) load
// (all 32 lanes same address -> HW broadcast) + one 16B/8B row load; 4-deep unroll
// into 2 accumulator banks. No shuffles, no batch staging.
__device__ __forceinline__ void fma8(float* a, const uint4& v, float w) {
    a[0] += bf2f((u16)v.x) * w; a[1] += bf2f((u16)(v.x >> 16)) * w;
    a[2] += bf2f((u16)v.y) * w; a[3] += bf2f((u16)(v.y >> 16)) * w;
    a[4] += bf2f((u16)v.z) * w; a[5] += bf2f((u16)(v.z >> 16)) * w;
    a[6] += bf2f((u16)v.w) * w; a[7] += bf2f((u16)(v.w >> 16)) * w;
}
__device__ __forceinline__ void fma4(float* a, const uint2& v, float w) {
    a[0] += bf2f((u16)v.x) * w; a[1] += bf2f((u16)(v.x >> 16)) * w;
    a[2] += bf2f((u16)v.y) * w; a[3] += bf2f((u16)(v.y >> 16)) * w;
}

template<int C>   // C=256: uint4/lane (8 bf16); C=128: uint2/lane (4 bf16)
__global__ __launch_bounds__(256)
void k_agg_gather(const int* __restrict__ rowptr, const uint2* __restrict__ csr2,
                  const float* __restrict__ dinv, const u16* __restrict__ hb,
                  u16* __restrict__ out, int n) {
    constexpr int VL = C / 32;           // bf16 per lane (8 or 4)
    int tid = threadIdx.x;
    int node = (blockIdx.x * 256 + tid) >> 5;
    if (node >= n) return;
    int sl = tid & 31;                   // lane within node's 32-lane group
    int beg = rowptr[node];
    int m = rowptr[node + 1] - beg;
    float di = dinv[node];
    float a0[VL], a1[VL];
    if constexpr (VL == 8) {
        uint4 v = ((const uint4*)hb)[(size_t)node * 32 + sl];
#pragma unroll
        for (int i = 0; i < 8; ++i) a1[i] = 0.f;
        a0[0] = bf2f((u16)v.x) * di; a0[1] = bf2f((u16)(v.x >> 16)) * di;
        a0[2] = bf2f((u16)v.y) * di; a0[3] = bf2f((u16)(v.y >> 16)) * di;
        a0[4] = bf2f((u16)v.z) * di; a0[5] = bf2f((u16)(v.z >> 16)) * di;
        a0[6] = bf2f((u16)v.w) * di; a0[7] = bf2f((u16)(v.w >> 16)) * di;
    } else {
        uint2 v = ((const uint2*)hb)[(size_t)node * 32 + sl];
#pragma unroll
        for (int i = 0; i < 4; ++i) a1[i] = 0.f;
        a0[0] = bf2f((u16)v.x) * di; a0[1] = bf2f((u16)(v.x >> 16)) * di;
        a0[2] = bf2f((u16)v.y) * di; a0[3] = bf2f((u16)(v.y >> 16)) * di;
    }
    const uint2* ep = csr2 + beg;
    int e = 0;
    for (; e + 4 <= m; e += 4) {
        uint2 e0 = ep[e], e1 = ep[e + 1], e2 = ep[e + 2], e3 = ep[e + 3];
        float w0 = __uint_as_float(e0.y), w1 = __uint_as_float(e1.y);
        float w2 = __uint_as_float(e2.y), w3 = __uint_as_float(e3.y);
        if constexpr (VL == 8) {
            uint4 r0 = ((const uint4*)hb)[(size_t)e0.x * 32 + sl];
            uint4 r1 = ((const uint4*)hb)[(size_t)e1.x * 32 + sl];
            uint4 r2 = ((const uint4*)hb)[(size_t)e2.x * 32 + sl];
            uint4 r3 = ((const uint4*)hb)[(size_t)e3.x * 32 + sl];
            fma8(a0, r0, w0); fma8(a1, r1, w1); fma8(a0, r2, w2); fma8(a1, r3, w3);
        } else {
            uint2 r0 = ((const uint2*)hb)[(size_t)e0.x * 32 + sl];
            uint2 r1 = ((const uint2*)hb)[(size_t)e1.x * 32 + sl];
            uint2 r2 = ((const uint2*)hb)[(size_t)e2.x * 32 + sl];
            uint2 r3 = ((const uint2*)hb)[(size_t)e3.x * 32 + sl];
            fma4(a0, r0, w0); fma4(a1, r1, w1); fma4(a0, r2, w2); fma4(a1, r3, w3);
        }
    }
    for (; e < m; ++e) {
        uint2 e0 = ep[e];
        float w0 = __uint_as_float(e0.y);
        if constexpr (VL == 8) {
            uint4 r0 = ((const uint4*)hb)[(size_t)e0.x * 32 + sl];
            fma8(a0, r0, w0);
        } else {
            uint2 r0 = ((const uint2*)hb)[(size_t)e0.x * 32 + sl];
            fma4(a0, r0, w0);
        }
    }
    if constexpr (VL == 8) {
        uint4 o;
        o.x = (u32)f2bf((a0[0] + a1[0]) * di) | ((u32)f2bf((a0[1] + a1[1]) * di) << 16);
        o.y = (u32)f2bf((a0[2] + a1[2]) * di) | ((u32)f2bf((a0[3] + a1[3]) * di) << 16);
        o.z = (u32)f2bf((a0[4] + a1[4]) * di) | ((u32)f2bf((a0[5] + a1[5]) * di) << 16);
        o.w = (u32)f2bf((a0[6] + a1[6]) * di) | ((u32)f2bf((a0[7] + a1[7]) * di) << 16);
        ((uint4*)out)[(size_t)node * 32 + sl] = o;
    } else {
        uint2 o;
        o.x = (u32)f2bf((a0[0] + a1[0]) * di) | ((u32)f2bf((a0[1] + a1[1]) * di) << 16);
        o.y = (u32)f2bf((a0[2] + a1[2]) * di) | ((u32)f2bf((a0[3] + a1[3]) * di) << 16);
        ((uint2*)out)[(size_t)node * 32 + sl] = o;
    }
}

// ---------------- MFMA GEMM (R9 structure, single-bf16 B) ----------------
// BM=128, BN=256, BK=32, 512 thr / 8 waves. A staged in 16KB dbuf LDS via
// global_load_lds (64B-granular chunks, XOR source-slot swizzle -> <=2-way ds_read
// conflicts). B = pre-tiled [kgrp][n][8] bf16, read straight to VGPRs from L2.
template<bool POOL>
__global__ __launch_bounds__(512, 4)
void k_gemm_mfma(const u16* __restrict__ A, const u16* __restrict__ Bh,
                 const float* __restrict__ bias, u16* __restrict__ out_bf,
                 const int* __restrict__ batch, float* __restrict__ pool,
                 int M, int K) {
    __shared__ u16 ldsA[2][4096];   // 2 x 8KB: [128 rows][4 slots of 8 bf16]
    const int tid = threadIdx.x, lane = tid & 63, wid = tid >> 6;
    const int bm = blockIdx.x * 128;
    const int wr = (wid >> 2) * 64, wc = (wid & 3) * 64;
    const int lr = lane & 15, kg = lane >> 4;

    const int srow = wid * 16 + (lane >> 2);            // local row 0..127
    const int sslot = lane & 3;
    const int ssw = (srow ^ (srow >> 2)) & 3;
    int srg = bm + srow; if (srg >= M) srg = M - 1;
    const u16* sbase = A + (size_t)srg * K + ((sslot ^ ssw) << 3);

    const u16* bh_p = Bh + (u32)kg * 2048 + (u32)(wc + lr) * 8;

    f32x4 acc[4][4];
#pragma unroll
    for (int i = 0; i < 4; ++i)
#pragma unroll
        for (int j = 0; j < 4; ++j) acc[i][j] = (f32x4){0.f, 0.f, 0.f, 0.f};

    const int nt = K >> 5;
    gll16(sbase, &ldsA[0][wid * 512]);
    __syncthreads();

    for (int t = 0; t < nt; ++t) {
        int cur = t & 1;
        if (t + 1 < nt)
            gll16(sbase + ((t + 1) << 5), &ldsA[cur ^ 1][wid * 512]);

        s16x8 bh[4];
#pragma unroll
        for (int fn = 0; fn < 4; ++fn)
            bh[fn] = *(const s16x8*)&bh_p[(u32)t * 8192 + (u32)fn * 128];
        const u16* lb = ldsA[cur];
        s16x8 a[4];
#pragma unroll
        for (int fm = 0; fm < 4; ++fm) {
            int r = wr + fm * 16 + lr;
            a[fm] = *(const s16x8*)&lb[r * 32 + ((kg ^ ((r ^ (r >> 2)) & 3)) << 3)];
        }
#pragma unroll
        for (int fn = 0; fn < 4; ++fn)
#pragma unroll
            for (int fm = 0; fm < 4; ++fm)
                acc[fm][fn] = __builtin_amdgcn_mfma_f32_16x16x32_bf16(a[fm], bh[fn], acc[fm][fn], 0, 0, 0);
        __syncthreads();
    }

    // epilogue: row = bm + wr + fm*16 + kg*4 + r ; col = wc + fn*16 + lr
#pragma unroll
    for (int fn = 0; fn < 4; ++fn) {
        int col = wc + fn * 16 + lr;
        float bv = bias[col];
        if (!POOL) {
#pragma unroll
            for (int fm = 0; fm < 4; ++fm) {
                int rbase = bm + wr + fm * 16 + kg * 4;
#pragma unroll
                for (int r = 0; r < 4; ++r) {
                    int row = rbase + r;
                    if (row < M)
                        out_bf[(size_t)row * 256 + col] = f2bf(fmaxf(acc[fm][fn][r] + bv, 0.f));
                }
            }
        } else {
            int gcur = -1;
            float run = 0.f;
#pragma unroll
            for (int fm = 0; fm < 4; ++fm) {
                int rbase = bm + wr + fm * 16 + kg * 4;
#pragma unroll
                for (int r = 0; r < 4; ++r) {
                    int row = rbase + r;
                    if (row < M) {
                        int g = batch[row];
                        float v = fmaxf(acc[fm][fn][r] + bv, 0.f);
                        if (g != gcur) {
                            if (gcur >= 0) atomicAdd(&pool[gcur * 256 + col], run);
                            gcur = g;
                            run = 0.f;
                        }
                        run += v;
                    }
                }
            }
            if (gcur >= 0) atomicAdd(&pool[gcur * 256 + col], run);
        }
    }
}

// ---------------- dense head ----------------
__global__ __launch_bounds__(128)
void k_dense(const float* __restrict__ sums, const float* __restrict__ counts,
             const float* __restrict__ W3, const float* __restrict__ b3,
             const float* __restrict__ W4, const float* __restrict__ b4,
             float* __restrict__ out) {
    __shared__ float g[256];
    __shared__ float hid[128];
    int gi = blockIdx.x;
    int t = threadIdx.x;
    float inv = 1.0f / fmaxf(counts[gi], 1.0f);
    for (int c = t; c < 256; c += 128) g[c] = sums[gi * 256 + c] * inv;
    __syncthreads();
    float acc = b3[t];
    for (int k = 0; k < 256; ++k) acc += g[k] * W3[k * 128 + t];
    hid[t] = fmaxf(acc, 0.0f);
    __syncthreads();
    if (t < 10) {
        float o = b4[t];
        for (int k = 0; k < 128; ++k) o += hid[k] * W4[k * 10 + t];
        out[gi * 10 + t] = o;
    }
}

extern "C" void kernel_launch(void* const* d_in, const int* in_sizes, int n_in,
                              void* d_out, int out_size, void* d_ws, size_t ws_size,
                              hipStream_t stream) {
    const float* x   = (const float*)d_in[0];
    const int*  eidx = (const int*)d_in[1];    // [2, NE]
    const int*  batch= (const int*)d_in[2];
    const float* W1 = (const float*)d_in[3];
    const float* b1 = (const float*)d_in[4];
    const float* W2 = (const float*)d_in[5];
    const float* b2 = (const float*)d_in[6];
    const float* W3 = (const float*)d_in[7];
    const float* b3 = (const float*)d_in[8];
    const float* W4 = (const float*)d_in[9];
    const float* b4 = (const float*)d_in[10];
    float* out = (float*)d_out;

    const int N = NN, E = NE, G = NG;
    const int* src = eidx;
    const int* dst = eidx + E;
    const int NB = (N + 255) / 256;

    // workspace layout (256B-aligned slices)
    char* p = (char*)d_ws;
    auto alloc = [&](size_t bytes) { char* r = p; p += (bytes + 255) & ~(size_t)255; return r; };
    u16*   h1bf   = (u16*)alloc((size_t)N * 256 * 2);   // bf16 h1 row-major
    u16*   xbf    = (u16*)alloc((size_t)N * 128 * 2);   // bf16 x row-major
    float* dinv   = (float*)alloc((size_t)N * 4);
    float* sums   = (float*)alloc((size_t)G * 256 * 4);
    float* counts = (float*)alloc((size_t)G * 4);
    int*   cnt    = (int*)alloc((size_t)N * 4);         // reused as cursor after scan
    int*   rowptr = (int*)alloc((size_t)(N + 1) * 4);
    int*   bsum   = (int*)alloc((size_t)NB * 4);
    uint2* csr2   = (uint2*)alloc((size_t)E * 8);       // (src, dinv[src])
    u16*   agg1   = (u16*)alloc((size_t)N * 128 * 2);   // row-major aggregated x
    u16*   agg2   = (u16*)alloc((size_t)N * 256 * 2);   // row-major aggregated h1
    u16*   w1hi   = (u16*)alloc((size_t)256 * 128 * 2); // pre-tiled [kgrp][n][8]
    u16*   w2hi   = (u16*)alloc((size_t)256 * 256 * 2);
    int*   cursor = cnt;

    // fused preamble: xbf, tiled wsplits (single bf16), zero sums, zero cnt, counts
    const int XB = (NN * 32 + 255) / 256;
    const int CB = (NN + 255) / 256;
    int pre_blocks = XB + 16 + 32 + 64 + CB + 1;
    k_preamble<<<pre_blocks, 256, 0, stream>>>(x, xbf, W1, w1hi, W2, w2hi,
                                               sums, cnt, batch, counts);

    // CSR build + dinv
    k_hist<<<(E + 255) / 256, 256, 0, stream>>>(dst, cnt, E);
    k_scan1<<<NB, 256, 0, stream>>>(cnt, bsum, N);
    k_scan2<<<1, 256, 0, stream>>>(bsum, NB);
    k_scan3<<<NB, 256, 0, stream>>>(cnt, bsum, rowptr, cursor, dinv, N);
    k_fill<<<(E + 255) / 256, 256, 0, stream>>>(src, dst, dinv, cursor, csr2, E);

    // conv1: gather-aggregate xbf (128ch, 2 nodes/wave) -> bf16 A, GEMM K=128 -> h1bf
    k_agg_gather<128><<<(N + 7) / 8, 256, 0, stream>>>(rowptr, csr2, dinv, xbf, agg1, N);
    int gblocks = (N + 127) / 128;
    k_gemm_mfma<false><<<gblocks, 512, 0, stream>>>(agg1, w1hi, b1, h1bf,
                                                    nullptr, nullptr, N, 128);

    // conv2: gather-aggregate h1bf (256ch, 2 nodes/wave) -> bf16 A, GEMM K=256 + pool
    k_agg_gather<256><<<(N + 7) / 8, 256, 0, stream>>>(rowptr, csr2, dinv, h1bf, agg2, N);
    k_gemm_mfma<true><<<gblocks, 512, 0, stream>>>(agg2, w2hi, b2, nullptr,
                                                   batch, sums, N, 256);

    // dense head
    k_dense<<<G, 128, 0, stream>>>(sums, counts, W3, b3, W4, b4, out);
}